// Round 10
// baseline (206.740 us; speedup 1.0000x reference)
//
#include <hip/hip_runtime.h>

// GraphSAGE 2-layer (mean agg), N=100K, E=1.6M, 128->128->64, f32 in/out.
// GEMMs in bf16 MFMA, FUSED: GEMM1 (K=256, [h|agg]@Wt1,+b1,relu) -> h1 tile in
// LDS -> GEMM2 (K=128, h1@Wt2cat) -> {p2 fp8, s2 f32} in one kernel.
// R10: BM=64 tile, W loaded direct from global (no WsB staging, no W barriers)
// -> 24 KB LDS -> 6 blocks/CU (was 2) to hide staging latency via TLP.
// Gather path fp8 e4m3, lane-group-per-node. CSR via bucketed counting sort.
// Overlays: p8->bed (dead after CSR), s2f->aggb (block-local rows, WAR-safe).

typedef __attribute__((ext_vector_type(8))) short short8;
typedef __attribute__((ext_vector_type(4))) float f32x4;
typedef __attribute__((ext_vector_type(2))) float f32x2;

__device__ __forceinline__ ushort f2bf(float f) {
  uint u = __float_as_uint(f);
  u += 0x7fffu + ((u >> 16) & 1u);  // round-to-nearest-even
  return (ushort)(u >> 16);
}

#define GLDS(src, dst)                                                        \
  __builtin_amdgcn_global_load_lds(                                           \
      (const __attribute__((address_space(1))) void*)(src),                   \
      (__attribute__((address_space(3))) void*)(dst), 16, 0, 0)

// ================= bucketed CSR build =================
__global__ __launch_bounds__(256) void k_bhist(const int* __restrict__ dst,
                                               int* __restrict__ bcnt, int E) {
  __shared__ int h[512];
  int t = threadIdx.x;
  for (int i = t; i < 512; i += 256) h[i] = 0;
  __syncthreads();
  int base = blockIdx.x * 8192;
  int end = min(base + 8192, E);
  for (int e = base + t; e < end; e += 256)
    atomicAdd(&h[((uint)dst[e]) >> 8], 1);
  __syncthreads();
  for (int i = t; i < 512; i += 256)
    if (h[i]) atomicAdd(&bcnt[i], h[i]);
}

__global__ __launch_bounds__(512) void k_bscan(const int* __restrict__ bcnt,
                                               int* __restrict__ bbase,
                                               int* __restrict__ bcur, int P, int E) {
  __shared__ int s[512];
  int t = threadIdx.x;
  int v = (t < P) ? bcnt[t] : 0;
  s[t] = v;
  __syncthreads();
  for (int off = 1; off < 512; off <<= 1) {
    int x = (t >= off) ? s[t - off] : 0;
    __syncthreads();
    s[t] += x;
    __syncthreads();
  }
  int ex = s[t] - v;
  if (t < P) {
    bbase[t] = ex;
    bcur[t] = ex;
  }
  if (t == P - 1) bbase[P] = E;
}

__global__ __launch_bounds__(256) void k_bscatter(const int* __restrict__ dst,
                                                  const int* __restrict__ src,
                                                  int* __restrict__ bcur,
                                                  uint* __restrict__ bed, int E, int P) {
  __shared__ int hist[512];
  __shared__ int incl[512];
  __shared__ int gpos[512];
  __shared__ int cur[512];
  __shared__ uint stage[8192];
  __shared__ ushort bof[8192];
  int t = threadIdx.x;
  int base = blockIdx.x * 8192;
  int cnt = min(8192, E - base);
  for (int i = t; i < 512; i += 256) hist[i] = 0;
  __syncthreads();
  for (int i = t; i < cnt; i += 256)
    atomicAdd(&hist[((uint)dst[base + i]) >> 8], 1);
  __syncthreads();
  incl[t] = hist[t];
  incl[t + 256] = hist[t + 256];
  __syncthreads();
  for (int off = 1; off < 512; off <<= 1) {
    int i0 = t, i1 = t + 256;
    int a0 = (i0 >= off) ? incl[i0 - off] : 0;
    int a1 = (i1 >= off) ? incl[i1 - off] : 0;
    __syncthreads();
    incl[i0] += a0;
    incl[i1] += a1;
    __syncthreads();
  }
  cur[t] = incl[t] - hist[t];
  cur[t + 256] = incl[t + 256] - hist[t + 256];
  for (int i = t; i < P; i += 256)
    if (hist[i]) gpos[i] = atomicAdd(&bcur[i], hist[i]);
  __syncthreads();
  for (int i = t; i < cnt; i += 256) {
    int d = dst[base + i];
    int b = ((uint)d) >> 8;
    uint val = (((uint)src[base + i]) << 8) | (uint)(d & 255);
    int slot = atomicAdd(&cur[b], 1);
    stage[slot] = val;
    bof[slot] = (ushort)b;
  }
  __syncthreads();
  for (int i = t; i < cnt; i += 256) {
    int b = bof[i];
    int ex = incl[b] - hist[b];
    bed[gpos[b] + (i - ex)] = stage[i];
  }
}

__global__ __launch_bounds__(256) void k_bcsr(const uint* __restrict__ bed,
                                              const int* __restrict__ bbase,
                                              int* __restrict__ deg,
                                              int* __restrict__ rs,
                                              int* __restrict__ col, int N) {
  __shared__ int dcnt[256];
  __shared__ int sofs[256];
  int b = blockIdx.x, t = threadIdx.x;
  int e0 = bbase[b], e1 = bbase[b + 1];
  dcnt[t] = 0;
  __syncthreads();
  for (int e = e0 + t; e < e1; e += 256) atomicAdd(&dcnt[bed[e] & 255u], 1);
  __syncthreads();
  int v0 = dcnt[t];
  sofs[t] = v0;
  __syncthreads();
  for (int off = 1; off < 256; off <<= 1) {
    int x = (t >= off) ? sofs[t - off] : 0;
    __syncthreads();
    sofs[t] += x;
    __syncthreads();
  }
  int ex = sofs[t] - v0;
  int node = (b << 8) + t;
  if (node < N) {
    deg[node] = v0;
    rs[node] = e0 + ex;
  }
  __syncthreads();
  dcnt[t] = e0 + ex;
  __syncthreads();
  for (int e = e0 + t; e < e1; e += 256) {
    uint v = bed[e];
    int pos = atomicAdd(&dcnt[v & 255u], 1);
    col[pos] = (int)(v >> 8);
  }
}

// -------- prep: f32 h -> bf16 hb (GEMM) + fp8 h8 (gather) --------
__global__ __launch_bounds__(256) void k_cast(const float* __restrict__ in,
                                              ushort* __restrict__ outb,
                                              uchar* __restrict__ out8, int n8) {
  int i = blockIdx.x * 256 + threadIdx.x;
  if (i >= n8) return;
  const float4* p = reinterpret_cast<const float4*>(in) + i * 2;
  float4 a = p[0], b = p[1];
  ushort u[8];
  u[0] = f2bf(a.x); u[1] = f2bf(a.y); u[2] = f2bf(a.z); u[3] = f2bf(a.w);
  u[4] = f2bf(b.x); u[5] = f2bf(b.y); u[6] = f2bf(b.z); u[7] = f2bf(b.w);
  *reinterpret_cast<ulonglong2*>(outb + (size_t)i * 8) =
      *reinterpret_cast<ulonglong2*>(u);
  uint2 q;
  int w0 = __builtin_amdgcn_cvt_pk_fp8_f32(a.x, a.y, 0, false);
  w0 = __builtin_amdgcn_cvt_pk_fp8_f32(a.z, a.w, w0, true);
  int w1 = __builtin_amdgcn_cvt_pk_fp8_f32(b.x, b.y, 0, false);
  w1 = __builtin_amdgcn_cvt_pk_fp8_f32(b.z, b.w, w1, true);
  q.x = (uint)w0;
  q.y = (uint)w1;
  *reinterpret_cast<uint2*>(out8 + (size_t)i * 8) = q;
}

// prep weights: Wt1[n][k0..255] = [Ws1;Wn1]^T ; Wt2cat[n][k0..127]:
// n<64 -> Wn2[k][n] (p2 half), n>=64 -> Ws2[k][n-64] (s2 half).
__global__ __launch_bounds__(256) void k_prep_w(const float* __restrict__ Ws1,
                                                const float* __restrict__ Wn1,
                                                const float* __restrict__ Ws2,
                                                const float* __restrict__ Wn2,
                                                ushort* __restrict__ Wt1,
                                                ushort* __restrict__ Wt2cat) {
  int idx = blockIdx.x * 256 + threadIdx.x;
  if (idx < 128 * 256) {
    int n = idx >> 8, k = idx & 255;
    float v = (k < 128) ? Ws1[(size_t)k * 128 + n] : Wn1[(size_t)(k - 128) * 128 + n];
    Wt1[idx] = f2bf(v);
  } else if (idx < 128 * 256 + 128 * 128) {
    int j = idx - 128 * 256;
    int n = j >> 7, k = j & 127;
    float v = (n < 64) ? Wn2[(size_t)k * 64 + n] : Ws2[(size_t)k * 64 + (n - 64)];
    Wt2cat[j] = f2bf(v);
  }
}

#define ACC16(v)                                                               \
  do {                                                                         \
    f32x2 f;                                                                   \
    f = __builtin_amdgcn_cvt_pk_f32_fp8((int)(v).x, false); a[0] += f.x; a[1] += f.y;  \
    f = __builtin_amdgcn_cvt_pk_f32_fp8((int)(v).x, true);  a[2] += f.x; a[3] += f.y;  \
    f = __builtin_amdgcn_cvt_pk_f32_fp8((int)(v).y, false); a[4] += f.x; a[5] += f.y;  \
    f = __builtin_amdgcn_cvt_pk_f32_fp8((int)(v).y, true);  a[6] += f.x; a[7] += f.y;  \
    f = __builtin_amdgcn_cvt_pk_f32_fp8((int)(v).z, false); a[8] += f.x; a[9] += f.y;  \
    f = __builtin_amdgcn_cvt_pk_f32_fp8((int)(v).z, true);  a[10] += f.x; a[11] += f.y;\
    f = __builtin_amdgcn_cvt_pk_f32_fp8((int)(v).w, false); a[12] += f.x; a[13] += f.y;\
    f = __builtin_amdgcn_cvt_pk_f32_fp8((int)(v).w, true);  a[14] += f.x; a[15] += f.y;\
  } while (0)

// -------- layer-1 aggregate: fp8 128B rows; 8-lane group per node ---------
__global__ __launch_bounds__(256) void k_agg1(const uchar* __restrict__ X8,
                                              const int* __restrict__ col,
                                              const int* __restrict__ rs,
                                              const int* __restrict__ deg,
                                              ushort* __restrict__ outb, int n) {
  int node = blockIdx.x * 32 + (threadIdx.x >> 3);
  if (node >= n) return;
  int sl = threadIdx.x & 7;
  int gbase = (threadIdx.x & 63) & ~7;  // group base lane within wave
  int r0 = rs[node], d = deg[node];
  float a[16] = {};
  int j = 0;
  while (j < d) {  // group-uniform bound (d uniform within group)
    int cnt = min(d - j, 8);
    int myc = (sl < cnt) ? col[r0 + j + sl] : 0;
    int jj = 0;
    for (; jj + 4 <= cnt; jj += 4) {
      int c0 = __shfl(myc, gbase + jj + 0, 64);
      int c1 = __shfl(myc, gbase + jj + 1, 64);
      int c2 = __shfl(myc, gbase + jj + 2, 64);
      int c3 = __shfl(myc, gbase + jj + 3, 64);
      uint4 v0 = *reinterpret_cast<const uint4*>(X8 + (size_t)c0 * 128 + sl * 16);
      uint4 v1 = *reinterpret_cast<const uint4*>(X8 + (size_t)c1 * 128 + sl * 16);
      uint4 v2 = *reinterpret_cast<const uint4*>(X8 + (size_t)c2 * 128 + sl * 16);
      uint4 v3 = *reinterpret_cast<const uint4*>(X8 + (size_t)c3 * 128 + sl * 16);
      { uint4 v = v0; ACC16(v); }
      { uint4 v = v1; ACC16(v); }
      { uint4 v = v2; ACC16(v); }
      { uint4 v = v3; ACC16(v); }
    }
    for (; jj < cnt; jj++) {  // group-uniform tail; shfl sources in-group, active
      int c0 = __shfl(myc, gbase + jj, 64);
      uint4 v = *reinterpret_cast<const uint4*>(X8 + (size_t)c0 * 128 + sl * 16);
      ACC16(v);
    }
    j += cnt;
  }
  float rinv = 1.0f / fmaxf((float)d, 1.0f);
  ushort o[16];
#pragma unroll
  for (int k = 0; k < 16; k++) o[k] = f2bf(a[k] * rinv);
  ulonglong2* dst = reinterpret_cast<ulonglong2*>(outb + (size_t)node * 128 + sl * 16);
  dst[0] = reinterpret_cast<ulonglong2*>(o)[0];
  dst[1] = reinterpret_cast<ulonglong2*>(o)[1];
}

// -------- layer-2 fused gather+add: fp8 64B rows; 4-lane group per node ----
__global__ __launch_bounds__(256) void k_agg_out(const uchar* __restrict__ P8,
                                                 const float* __restrict__ S,
                                                 const int* __restrict__ col,
                                                 const int* __restrict__ rs,
                                                 const int* __restrict__ deg,
                                                 float* __restrict__ out, int n) {
  int node = blockIdx.x * 64 + (threadIdx.x >> 2);
  if (node >= n) return;
  int sl = threadIdx.x & 3;
  int gbase = (threadIdx.x & 63) & ~3;
  int r0 = rs[node], d = deg[node];
  float a[16] = {};
  int j = 0;
  while (j < d) {
    int cnt = min(d - j, 4);
    int myc = (sl < cnt) ? col[r0 + j + sl] : 0;
    int jj = 0;
    for (; jj + 4 <= cnt; jj += 4) {
      int c0 = __shfl(myc, gbase + 0, 64);
      int c1 = __shfl(myc, gbase + 1, 64);
      int c2 = __shfl(myc, gbase + 2, 64);
      int c3 = __shfl(myc, gbase + 3, 64);
      uint4 v0 = *reinterpret_cast<const uint4*>(P8 + (size_t)c0 * 64 + sl * 16);
      uint4 v1 = *reinterpret_cast<const uint4*>(P8 + (size_t)c1 * 64 + sl * 16);
      uint4 v2 = *reinterpret_cast<const uint4*>(P8 + (size_t)c2 * 64 + sl * 16);
      uint4 v3 = *reinterpret_cast<const uint4*>(P8 + (size_t)c3 * 64 + sl * 16);
      { uint4 v = v0; ACC16(v); }
      { uint4 v = v1; ACC16(v); }
      { uint4 v = v2; ACC16(v); }
      { uint4 v = v3; ACC16(v); }
    }
    for (; jj < cnt; jj++) {
      int c0 = __shfl(myc, gbase + jj, 64);
      uint4 v = *reinterpret_cast<const uint4*>(P8 + (size_t)c0 * 64 + sl * 16);
      ACC16(v);
    }
    j += cnt;
  }
  float rinv = 1.0f / fmaxf((float)d, 1.0f);
  const float4* sp = reinterpret_cast<const float4*>(S + (size_t)node * 64 + sl * 16);
  float4* op = reinterpret_cast<float4*>(out + (size_t)node * 64 + sl * 16);
#pragma unroll
  for (int q = 0; q < 4; q++) {
    float4 s = sp[q];
    float4 o;
    o.x = fmaxf(a[q * 4 + 0] * rinv + s.x, 0.f);
    o.y = fmaxf(a[q * 4 + 1] * rinv + s.y, 0.f);
    o.z = fmaxf(a[q * 4 + 2] * rinv + s.z, 0.f);
    o.w = fmaxf(a[q * 4 + 3] * rinv + s.w, 0.f);
    op[q] = o;
  }
}

// ---------------- FUSED MFMA combine (BM=64, W direct from global) ---------
// GEMM1: [Xb|Gb] (K=256) @ Wt1 -> +b1, relu -> h1 tile in LDS Xs2 (swizzled).
// GEMM2: Xs2 (K=128) @ Wt2cat -> cols<64: p2 fp8; cols>=64: s2 = acc+b2 f32.
// 24 KB LDS -> 6 blocks/CU. B-fragments read straight from global (L1/L2-hot).
__global__ __launch_bounds__(256) void k_fused(const ushort* __restrict__ Xb,
                                               const ushort* __restrict__ Gb,
                                               const ushort* __restrict__ Wt1,
                                               const ushort* __restrict__ Wt2,
                                               const float* __restrict__ b1,
                                               const float* __restrict__ b2,
                                               uchar* __restrict__ P8,
                                               float* __restrict__ S2, int M) {
  __shared__ char XsB[64 * 64 * 2];   // 8 KB: X-tile K-chunk
  __shared__ char Xs2[64 * 128 * 2];  // 16 KB: h1 tile (A for GEMM2)

  const int m0 = blockIdx.x * 64;
  const int t = threadIdx.x;
  const int lane = t & 63;
  const int w = t >> 6;
  const int wm = w >> 1, wn = w & 1;  // 2x2 wave grid: 32-row x 64-col tiles

  f32x4 acc[2][4] = {};

  // ---- GEMM1: K=256 over [Xb | Gb]; X staged, W direct ----
  for (int kc = 0; kc < 4; kc++) {
    const ushort* Xsrc = (kc < 2) ? Xb : Gb;
    const int koff = (kc & 1) * 64;
#pragma unroll
    for (int i = 0; i < 2; i++) {
      int g = i * 256 + t;
      int row = g >> 3, kph = g & 7;
      int gm = min(m0 + row, M - 1);
      const ushort* src = Xsrc + (size_t)gm * 128 + koff + ((kph ^ (row & 7)) << 3);
      char* dst = XsB + ((i * 256 + (t & ~63)) << 4);
      GLDS(src, dst);
    }
    __syncthreads();
#pragma unroll
    for (int ks = 0; ks < 2; ks++) {
      int kslot = ks * 4 + (lane >> 4);
      short8 af[2], bf[4];
#pragma unroll
      for (int fm = 0; fm < 2; fm++) {
        int row = wm * 32 + fm * 16 + (lane & 15);
        af[fm] = *reinterpret_cast<const short8*>(
            XsB + row * 128 + ((kslot ^ (row & 7)) << 4));
      }
#pragma unroll
      for (int fn = 0; fn < 4; fn++) {
        int colr = wn * 64 + fn * 16 + (lane & 15);
        bf[fn] = *reinterpret_cast<const short8*>(
            Wt1 + (size_t)colr * 256 + kc * 64 + kslot * 8);
      }
#pragma unroll
      for (int fm = 0; fm < 2; fm++)
#pragma unroll
        for (int fn = 0; fn < 4; fn++)
          acc[fm][fn] = __builtin_amdgcn_mfma_f32_16x16x32_bf16(
              af[fm], bf[fn], acc[fm][fn], 0, 0, 0);
    }
    __syncthreads();
  }

  // ---- epilogue 1: h1 = relu(acc + b1) -> Xs2 (swizzled bf16) ----
#pragma unroll
  for (int fn = 0; fn < 4; fn++) {
    int colg = wn * 64 + fn * 16 + (lane & 15);
    float bb = b1[colg];
    int g = colg >> 3;
    int cb = (colg & 7) * 2;
#pragma unroll
    for (int fm = 0; fm < 2; fm++) {
#pragma unroll
      for (int r = 0; r < 4; r++) {
        int rowl = wm * 32 + fm * 16 + (lane >> 4) * 4 + r;
        ushort hv = f2bf(fmaxf(acc[fm][fn][r] + bb, 0.f));
        *reinterpret_cast<ushort*>(Xs2 + rowl * 256 + ((g ^ (rowl & 15)) << 4) + cb) = hv;
      }
    }
  }
  __syncthreads();

  // ---- GEMM2: K=128, A from Xs2 (LDS), B direct from global; no barriers ----
  f32x4 acc2[2][4] = {};
#pragma unroll
  for (int ks = 0; ks < 4; ks++) {
    int gk = ks * 4 + (lane >> 4);  // 0..15 k-granule
    short8 af[2], bf[4];
#pragma unroll
    for (int fm = 0; fm < 2; fm++) {
      int row = wm * 32 + fm * 16 + (lane & 15);
      af[fm] = *reinterpret_cast<const short8*>(
          Xs2 + row * 256 + ((gk ^ (row & 15)) << 4));
    }
#pragma unroll
    for (int fn = 0; fn < 4; fn++) {
      int colr = wn * 64 + fn * 16 + (lane & 15);
      bf[fn] = *reinterpret_cast<const short8*>(
          Wt2 + (size_t)colr * 128 + gk * 8);
    }
#pragma unroll
    for (int fm = 0; fm < 2; fm++)
#pragma unroll
      for (int fn = 0; fn < 4; fn++)
        acc2[fm][fn] = __builtin_amdgcn_mfma_f32_16x16x32_bf16(
            af[fm], bf[fn], acc2[fm][fn], 0, 0, 0);
  }

  // ---- epilogue 2: split p2 (fp8) / s2 (f32 + b2) ----
#pragma unroll
  for (int fn = 0; fn < 4; fn++) {
    int colg = wn * 64 + fn * 16 + (lane & 15);
    float bb = (colg >= 64) ? b2[colg - 64] : 0.f;
#pragma unroll
    for (int fm = 0; fm < 2; fm++) {
#pragma unroll
      for (int r = 0; r < 4; r++) {
        int rowg = m0 + wm * 32 + fm * 16 + (lane >> 4) * 4 + r;
        if (rowg >= M) continue;
        if (colg < 64) {
          float v = acc2[fm][fn][r];
          int b8 = __builtin_amdgcn_cvt_pk_fp8_f32(v, v, 0, false);
          P8[(size_t)rowg * 64 + colg] = (uchar)(b8 & 0xff);
        } else {
          S2[(size_t)rowg * 64 + (colg - 64)] = acc2[fm][fn][r] + bb;
        }
      }
    }
  }
}

extern "C" void kernel_launch(void* const* d_in, const int* in_sizes, int n_in,
                              void* d_out, int out_size, void* d_ws, size_t ws_size,
                              hipStream_t stream) {
  const float* h = (const float*)d_in[0];
  const int* esrc = (const int*)d_in[1];
  const int* edst = (const int*)d_in[2];
  const float* Ws1 = (const float*)d_in[3];
  const float* Wn1 = (const float*)d_in[4];
  const float* b1 = (const float*)d_in[5];
  const float* Ws2 = (const float*)d_in[6];
  const float* Wn2 = (const float*)d_in[7];
  const float* b2 = (const float*)d_in[8];
  float* out = (float*)d_out;

  const int N = in_sizes[0] / 128;  // 100000
  const int E = in_sizes[1];        // 1600000
  const int P = (N + 255) >> 8;     // 391 buckets (<=512)

  char* base = (char*)d_ws;
  size_t off = 0;
  auto alloc = [&](size_t bytes) {
    size_t o = off;
    off += (bytes + 255) & ~(size_t)255;
    return o;
  };
  int* deg = (int*)(base + alloc((size_t)N * 4));
  int* rs = (int*)(base + alloc((size_t)N * 4));
  int* bcnt = (int*)(base + alloc(513 * 4));
  int* bbase = (int*)(base + alloc(513 * 4));
  int* bcur = (int*)(base + alloc(513 * 4));
  uint* bed = (uint*)(base + alloc((size_t)E * 4));
  int* col = (int*)(base + alloc((size_t)E * 4));
  ushort* hb = (ushort*)(base + alloc((size_t)N * 128 * 2));
  uchar* h8 = (uchar*)(base + alloc((size_t)N * 128));
  ushort* aggb = (ushort*)(base + alloc((size_t)N * 128 * 2));
  ushort* Wt1 = (ushort*)(base + alloc(128 * 256 * 2));
  ushort* Wt2cat = (ushort*)(base + alloc(128 * 128 * 2));
  // overlays:
  uchar* p8 = (uchar*)bed;   // [N][64] fp8: bed dead after k_bcsr; N*64 <= E*4
  float* s2f = (float*)aggb; // [N][64] f32: same 256B row stride as aggb; fused
                             // block overwrites exactly the rows it read (safe)

  const int NCH = (E + 8191) / 8192;

  (void)hipMemsetAsync(bcnt, 0, 513 * 4, stream);
  k_bhist<<<NCH, 256, 0, stream>>>(edst, bcnt, E);
  k_bscan<<<1, 512, 0, stream>>>(bcnt, bbase, bcur, P, E);
  k_bscatter<<<NCH, 256, 0, stream>>>(edst, esrc, bcur, bed, E, P);
  k_bcsr<<<P, 256, 0, stream>>>(bed, bbase, deg, rs, col, N);

  k_prep_w<<<((128 * 256 + 128 * 128) + 255) / 256, 256, 0, stream>>>(
      Ws1, Wn1, Ws2, Wn2, Wt1, Wt2cat);
  k_cast<<<((N * 128 / 8) + 255) / 256, 256, 0, stream>>>(h, hb, h8, N * 128 / 8);

  // Layer 1 aggregate, then fused GEMM1+GEMM2 -> p2 (fp8) + s2 (f32)
  k_agg1<<<(N + 31) / 32, 256, 0, stream>>>(h8, col, rs, deg, aggb, N);
  k_fused<<<(N + 63) / 64, 256, 0, stream>>>(hb, aggb, Wt1, Wt2cat, b1, b2,
                                             p8, s2f, N);
  // Layer 2 fused gather + add + relu
  k_agg_out<<<(N + 63) / 64, 256, 0, stream>>>(p8, s2f, col, rs, deg, out, N);
}

// Round 11
// 182.620 us; speedup vs baseline: 1.1321x; 1.1321x over previous
//
#include <hip/hip_runtime.h>

// GraphSAGE 2-layer (mean agg), N=100K, E=1.6M, 128->128->64, f32 in/out.
// PERSISTENT fused GEMM: 256 blocks x 512 thr (1/CU), W1+W2 resident in LDS
// (staged once), grid-stride over M-tiles (BM=64) with register-prefetch
// pipeline (issue next tile's global loads before compute, ds_write after
// barrier). Raw s_barrier + lgkmcnt asm (no vmcnt(0) drains of the prefetch).
// GEMM1 (K=256) -> h1 in LDS (reuses X buffer) -> GEMM2 (K=128) -> p2 fp8 + s2 f32.
// Gather path fp8 e4m3 lane-group-per-node. CSR via bucketed counting sort.
// Overlays: p8->bed (dead after CSR), s2f->aggb (row ranges block-local, WAR-safe).

typedef __attribute__((ext_vector_type(8))) short short8;
typedef __attribute__((ext_vector_type(4))) float f32x4;
typedef __attribute__((ext_vector_type(2))) float f32x2;

__device__ __forceinline__ ushort f2bf(float f) {
  uint u = __float_as_uint(f);
  u += 0x7fffu + ((u >> 16) & 1u);  // round-to-nearest-even
  return (ushort)(u >> 16);
}

#define GLDS(src, dst)                                                        \
  __builtin_amdgcn_global_load_lds(                                           \
      (const __attribute__((address_space(1))) void*)(src),                   \
      (__attribute__((address_space(3))) void*)(dst), 16, 0, 0)

#define FENCE() asm volatile("" ::: "memory")
#define LGKM0() asm volatile("s_waitcnt lgkmcnt(0)" ::: "memory")

// ================= bucketed CSR build =================
__global__ __launch_bounds__(256) void k_bhist(const int* __restrict__ dst,
                                               int* __restrict__ bcnt, int E) {
  __shared__ int h[512];
  int t = threadIdx.x;
  for (int i = t; i < 512; i += 256) h[i] = 0;
  __syncthreads();
  int base = blockIdx.x * 8192;
  int end = min(base + 8192, E);
  for (int e = base + t; e < end; e += 256)
    atomicAdd(&h[((uint)dst[e]) >> 8], 1);
  __syncthreads();
  for (int i = t; i < 512; i += 256)
    if (h[i]) atomicAdd(&bcnt[i], h[i]);
}

__global__ __launch_bounds__(512) void k_bscan(const int* __restrict__ bcnt,
                                               int* __restrict__ bbase,
                                               int* __restrict__ bcur, int P, int E) {
  __shared__ int s[512];
  int t = threadIdx.x;
  int v = (t < P) ? bcnt[t] : 0;
  s[t] = v;
  __syncthreads();
  for (int off = 1; off < 512; off <<= 1) {
    int x = (t >= off) ? s[t - off] : 0;
    __syncthreads();
    s[t] += x;
    __syncthreads();
  }
  int ex = s[t] - v;
  if (t < P) {
    bbase[t] = ex;
    bcur[t] = ex;
  }
  if (t == P - 1) bbase[P] = E;
}

__global__ __launch_bounds__(256) void k_bscatter(const int* __restrict__ dst,
                                                  const int* __restrict__ src,
                                                  int* __restrict__ bcur,
                                                  uint* __restrict__ bed, int E, int P) {
  __shared__ int hist[512];
  __shared__ int incl[512];
  __shared__ int gpos[512];
  __shared__ int cur[512];
  __shared__ uint stage[8192];
  __shared__ ushort bof[8192];
  int t = threadIdx.x;
  int base = blockIdx.x * 8192;
  int cnt = min(8192, E - base);
  for (int i = t; i < 512; i += 256) hist[i] = 0;
  __syncthreads();
  for (int i = t; i < cnt; i += 256)
    atomicAdd(&hist[((uint)dst[base + i]) >> 8], 1);
  __syncthreads();
  incl[t] = hist[t];
  incl[t + 256] = hist[t + 256];
  __syncthreads();
  for (int off = 1; off < 512; off <<= 1) {
    int i0 = t, i1 = t + 256;
    int a0 = (i0 >= off) ? incl[i0 - off] : 0;
    int a1 = (i1 >= off) ? incl[i1 - off] : 0;
    __syncthreads();
    incl[i0] += a0;
    incl[i1] += a1;
    __syncthreads();
  }
  cur[t] = incl[t] - hist[t];
  cur[t + 256] = incl[t + 256] - hist[t + 256];
  for (int i = t; i < P; i += 256)
    if (hist[i]) gpos[i] = atomicAdd(&bcur[i], hist[i]);
  __syncthreads();
  for (int i = t; i < cnt; i += 256) {
    int d = dst[base + i];
    int b = ((uint)d) >> 8;
    uint val = (((uint)src[base + i]) << 8) | (uint)(d & 255);
    int slot = atomicAdd(&cur[b], 1);
    stage[slot] = val;
    bof[slot] = (ushort)b;
  }
  __syncthreads();
  for (int i = t; i < cnt; i += 256) {
    int b = bof[i];
    int ex = incl[b] - hist[b];
    bed[gpos[b] + (i - ex)] = stage[i];
  }
}

__global__ __launch_bounds__(256) void k_bcsr(const uint* __restrict__ bed,
                                              const int* __restrict__ bbase,
                                              int* __restrict__ deg,
                                              int* __restrict__ rs,
                                              int* __restrict__ col, int N) {
  __shared__ int dcnt[256];
  __shared__ int sofs[256];
  int b = blockIdx.x, t = threadIdx.x;
  int e0 = bbase[b], e1 = bbase[b + 1];
  dcnt[t] = 0;
  __syncthreads();
  for (int e = e0 + t; e < e1; e += 256) atomicAdd(&dcnt[bed[e] & 255u], 1);
  __syncthreads();
  int v0 = dcnt[t];
  sofs[t] = v0;
  __syncthreads();
  for (int off = 1; off < 256; off <<= 1) {
    int x = (t >= off) ? sofs[t - off] : 0;
    __syncthreads();
    sofs[t] += x;
    __syncthreads();
  }
  int ex = sofs[t] - v0;
  int node = (b << 8) + t;
  if (node < N) {
    deg[node] = v0;
    rs[node] = e0 + ex;
  }
  __syncthreads();
  dcnt[t] = e0 + ex;
  __syncthreads();
  for (int e = e0 + t; e < e1; e += 256) {
    uint v = bed[e];
    int pos = atomicAdd(&dcnt[v & 255u], 1);
    col[pos] = (int)(v >> 8);
  }
}

// -------- prep: f32 h -> bf16 hb (GEMM) + fp8 h8 (gather) --------
__global__ __launch_bounds__(256) void k_cast(const float* __restrict__ in,
                                              ushort* __restrict__ outb,
                                              uchar* __restrict__ out8, int n8) {
  int i = blockIdx.x * 256 + threadIdx.x;
  if (i >= n8) return;
  const float4* p = reinterpret_cast<const float4*>(in) + i * 2;
  float4 a = p[0], b = p[1];
  ushort u[8];
  u[0] = f2bf(a.x); u[1] = f2bf(a.y); u[2] = f2bf(a.z); u[3] = f2bf(a.w);
  u[4] = f2bf(b.x); u[5] = f2bf(b.y); u[6] = f2bf(b.z); u[7] = f2bf(b.w);
  *reinterpret_cast<ulonglong2*>(outb + (size_t)i * 8) =
      *reinterpret_cast<ulonglong2*>(u);
  uint2 q;
  int w0 = __builtin_amdgcn_cvt_pk_fp8_f32(a.x, a.y, 0, false);
  w0 = __builtin_amdgcn_cvt_pk_fp8_f32(a.z, a.w, w0, true);
  int w1 = __builtin_amdgcn_cvt_pk_fp8_f32(b.x, b.y, 0, false);
  w1 = __builtin_amdgcn_cvt_pk_fp8_f32(b.z, b.w, w1, true);
  q.x = (uint)w0;
  q.y = (uint)w1;
  *reinterpret_cast<uint2*>(out8 + (size_t)i * 8) = q;
}

// prep weights: Wt1[n][k0..255] = [Ws1;Wn1]^T ; Wt2cat[n][k0..127]:
// n<64 -> Wn2[k][n] (p2 half), n>=64 -> Ws2[k][n-64] (s2 half).
__global__ __launch_bounds__(256) void k_prep_w(const float* __restrict__ Ws1,
                                                const float* __restrict__ Wn1,
                                                const float* __restrict__ Ws2,
                                                const float* __restrict__ Wn2,
                                                ushort* __restrict__ Wt1,
                                                ushort* __restrict__ Wt2cat) {
  int idx = blockIdx.x * 256 + threadIdx.x;
  if (idx < 128 * 256) {
    int n = idx >> 8, k = idx & 255;
    float v = (k < 128) ? Ws1[(size_t)k * 128 + n] : Wn1[(size_t)(k - 128) * 128 + n];
    Wt1[idx] = f2bf(v);
  } else if (idx < 128 * 256 + 128 * 128) {
    int j = idx - 128 * 256;
    int n = j >> 7, k = j & 127;
    float v = (n < 64) ? Wn2[(size_t)k * 64 + n] : Ws2[(size_t)k * 64 + (n - 64)];
    Wt2cat[j] = f2bf(v);
  }
}

#define ACC16(v)                                                               \
  do {                                                                         \
    f32x2 f;                                                                   \
    f = __builtin_amdgcn_cvt_pk_f32_fp8((int)(v).x, false); a[0] += f.x; a[1] += f.y;  \
    f = __builtin_amdgcn_cvt_pk_f32_fp8((int)(v).x, true);  a[2] += f.x; a[3] += f.y;  \
    f = __builtin_amdgcn_cvt_pk_f32_fp8((int)(v).y, false); a[4] += f.x; a[5] += f.y;  \
    f = __builtin_amdgcn_cvt_pk_f32_fp8((int)(v).y, true);  a[6] += f.x; a[7] += f.y;  \
    f = __builtin_amdgcn_cvt_pk_f32_fp8((int)(v).z, false); a[8] += f.x; a[9] += f.y;  \
    f = __builtin_amdgcn_cvt_pk_f32_fp8((int)(v).z, true);  a[10] += f.x; a[11] += f.y;\
    f = __builtin_amdgcn_cvt_pk_f32_fp8((int)(v).w, false); a[12] += f.x; a[13] += f.y;\
    f = __builtin_amdgcn_cvt_pk_f32_fp8((int)(v).w, true);  a[14] += f.x; a[15] += f.y;\
  } while (0)

// -------- layer-1 aggregate: fp8 128B rows; 8-lane group per node ---------
__global__ __launch_bounds__(256) void k_agg1(const uchar* __restrict__ X8,
                                              const int* __restrict__ col,
                                              const int* __restrict__ rs,
                                              const int* __restrict__ deg,
                                              ushort* __restrict__ outb, int n) {
  int node = blockIdx.x * 32 + (threadIdx.x >> 3);
  if (node >= n) return;
  int sl = threadIdx.x & 7;
  int gbase = (threadIdx.x & 63) & ~7;
  int r0 = rs[node], d = deg[node];
  float a[16] = {};
  int j = 0;
  while (j < d) {
    int cnt = min(d - j, 8);
    int myc = (sl < cnt) ? col[r0 + j + sl] : 0;
    int jj = 0;
    for (; jj + 4 <= cnt; jj += 4) {
      int c0 = __shfl(myc, gbase + jj + 0, 64);
      int c1 = __shfl(myc, gbase + jj + 1, 64);
      int c2 = __shfl(myc, gbase + jj + 2, 64);
      int c3 = __shfl(myc, gbase + jj + 3, 64);
      uint4 v0 = *reinterpret_cast<const uint4*>(X8 + (size_t)c0 * 128 + sl * 16);
      uint4 v1 = *reinterpret_cast<const uint4*>(X8 + (size_t)c1 * 128 + sl * 16);
      uint4 v2 = *reinterpret_cast<const uint4*>(X8 + (size_t)c2 * 128 + sl * 16);
      uint4 v3 = *reinterpret_cast<const uint4*>(X8 + (size_t)c3 * 128 + sl * 16);
      { uint4 v = v0; ACC16(v); }
      { uint4 v = v1; ACC16(v); }
      { uint4 v = v2; ACC16(v); }
      { uint4 v = v3; ACC16(v); }
    }
    for (; jj < cnt; jj++) {
      int c0 = __shfl(myc, gbase + jj, 64);
      uint4 v = *reinterpret_cast<const uint4*>(X8 + (size_t)c0 * 128 + sl * 16);
      ACC16(v);
    }
    j += cnt;
  }
  float rinv = 1.0f / fmaxf((float)d, 1.0f);
  ushort o[16];
#pragma unroll
  for (int k = 0; k < 16; k++) o[k] = f2bf(a[k] * rinv);
  ulonglong2* dst = reinterpret_cast<ulonglong2*>(outb + (size_t)node * 128 + sl * 16);
  dst[0] = reinterpret_cast<ulonglong2*>(o)[0];
  dst[1] = reinterpret_cast<ulonglong2*>(o)[1];
}

// -------- layer-2 fused gather+add: fp8 64B rows; 4-lane group per node ----
__global__ __launch_bounds__(256) void k_agg_out(const uchar* __restrict__ P8,
                                                 const float* __restrict__ S,
                                                 const int* __restrict__ col,
                                                 const int* __restrict__ rs,
                                                 const int* __restrict__ deg,
                                                 float* __restrict__ out, int n) {
  int node = blockIdx.x * 64 + (threadIdx.x >> 2);
  if (node >= n) return;
  int sl = threadIdx.x & 3;
  int gbase = (threadIdx.x & 63) & ~3;
  int r0 = rs[node], d = deg[node];
  float a[16] = {};
  int j = 0;
  while (j < d) {
    int cnt = min(d - j, 4);
    int myc = (sl < cnt) ? col[r0 + j + sl] : 0;
    int jj = 0;
    for (; jj + 4 <= cnt; jj += 4) {
      int c0 = __shfl(myc, gbase + 0, 64);
      int c1 = __shfl(myc, gbase + 1, 64);
      int c2 = __shfl(myc, gbase + 2, 64);
      int c3 = __shfl(myc, gbase + 3, 64);
      uint4 v0 = *reinterpret_cast<const uint4*>(P8 + (size_t)c0 * 64 + sl * 16);
      uint4 v1 = *reinterpret_cast<const uint4*>(P8 + (size_t)c1 * 64 + sl * 16);
      uint4 v2 = *reinterpret_cast<const uint4*>(P8 + (size_t)c2 * 64 + sl * 16);
      uint4 v3 = *reinterpret_cast<const uint4*>(P8 + (size_t)c3 * 64 + sl * 16);
      { uint4 v = v0; ACC16(v); }
      { uint4 v = v1; ACC16(v); }
      { uint4 v = v2; ACC16(v); }
      { uint4 v = v3; ACC16(v); }
    }
    for (; jj < cnt; jj++) {
      int c0 = __shfl(myc, gbase + jj, 64);
      uint4 v = *reinterpret_cast<const uint4*>(P8 + (size_t)c0 * 64 + sl * 16);
      ACC16(v);
    }
    j += cnt;
  }
  float rinv = 1.0f / fmaxf((float)d, 1.0f);
  const float4* sp = reinterpret_cast<const float4*>(S + (size_t)node * 64 + sl * 16);
  float4* op = reinterpret_cast<float4*>(out + (size_t)node * 64 + sl * 16);
#pragma unroll
  for (int q = 0; q < 4; q++) {
    float4 s = sp[q];
    float4 o;
    o.x = fmaxf(a[q * 4 + 0] * rinv + s.x, 0.f);
    o.y = fmaxf(a[q * 4 + 1] * rinv + s.y, 0.f);
    o.z = fmaxf(a[q * 4 + 2] * rinv + s.z, 0.f);
    o.w = fmaxf(a[q * 4 + 3] * rinv + s.w, 0.f);
    op[q] = o;
  }
}

// ---------------- PERSISTENT fused GEMM ----------------
// 256 blocks x 512 thr (8 waves: 2m x 4n, wave tile 32x32). W1s/W2s LDS-resident.
// Per tile (BM=64): GEMM1 K=256 -> h1 (LDS, reuses Xs) -> GEMM2 K=128 -> p8/s2.
// Register-prefetch of next tile's X hidden under compute; raw barriers.
__global__ __launch_bounds__(512) void k_persist(const ushort* __restrict__ Xb,
                                                 const ushort* __restrict__ Gb,
                                                 const ushort* __restrict__ Wt1,
                                                 const ushort* __restrict__ Wt2,
                                                 const float* __restrict__ b1,
                                                 const float* __restrict__ b2,
                                                 uchar* __restrict__ P8,
                                                 float* __restrict__ S2,
                                                 int M, int ntiles) {
  __shared__ ushort W1s[128 * 256];  // 64 KB, row=out-col n, 512B/row, swz gran^(n&7)
  __shared__ ushort W2s[128 * 128];  // 32 KB, 256B/row
  __shared__ char Xs[64 * 256 * 2];  // 32 KB X tile (512B/row); h1 reuses [0,16KB)

  const int t = threadIdx.x;
  const int lane = t & 63;
  const int w = t >> 6;
  const int wm = w >> 2, wn = w & 3;

  // ---- stage W once (GLDS) ----
#pragma unroll
  for (int i = 0; i < 8; i++) {  // W1: 4096 granules
    int g = t + 512 * i;
    int row = g >> 5, kph = g & 31;
    const ushort* src = Wt1 + (size_t)row * 256 + ((kph ^ (row & 7)) << 3);
    char* dst = (char*)W1s + ((g & ~63) << 4);
    GLDS(src, dst);
  }
#pragma unroll
  for (int i = 0; i < 4; i++) {  // W2: 2048 granules
    int g = t + 512 * i;
    int row = g >> 4, kph = g & 15;
    const ushort* src = Wt2 + (size_t)row * 128 + ((kph ^ (row & 7)) << 3);
    char* dst = (char*)W2s + ((g & ~63) << 4);
    GLDS(src, dst);
  }

  // per-thread bias preload (colg fixed per fn)
  float bb1[2], bb2[2];
#pragma unroll
  for (int fn = 0; fn < 2; fn++) {
    int colg = wn * 32 + fn * 16 + (lane & 15);
    bb1[fn] = b1[colg];
    bb2[fn] = (colg >= 64) ? b2[colg - 64] : 0.f;
  }

  int tile = blockIdx.x;
  if (tile >= ntiles) return;  // (never with 256 blocks, 1563 tiles)

  uint4 xr0, xr1, xr2, xr3;
  // X load: granule g in [0,2048): row=g>>5 (64 rows x 512B), kph=g&31.
  // K-halves: kph<16 -> Xb, else Gb; swizzle kph^(row&7) stays in-half.
#define LOADX(tl)                                                              \
  {                                                                            \
    int g, row, kk, gm;                                                        \
    const ushort* s;                                                           \
    g = t;            row = g >> 5; kk = (g & 31) ^ (row & 7);                 \
    gm = min((tl) * 64 + row, M - 1);                                          \
    s = (kk < 16) ? Xb + (size_t)gm * 128 + kk * 8                             \
                  : Gb + (size_t)gm * 128 + (kk - 16) * 8;                     \
    xr0 = *reinterpret_cast<const uint4*>(s);                                  \
    g = t + 512;      row = g >> 5; kk = (g & 31) ^ (row & 7);                 \
    gm = min((tl) * 64 + row, M - 1);                                          \
    s = (kk < 16) ? Xb + (size_t)gm * 128 + kk * 8                             \
                  : Gb + (size_t)gm * 128 + (kk - 16) * 8;                     \
    xr1 = *reinterpret_cast<const uint4*>(s);                                  \
    g = t + 1024;     row = g >> 5; kk = (g & 31) ^ (row & 7);                 \
    gm = min((tl) * 64 + row, M - 1);                                          \
    s = (kk < 16) ? Xb + (size_t)gm * 128 + kk * 8                             \
                  : Gb + (size_t)gm * 128 + (kk - 16) * 8;                     \
    xr2 = *reinterpret_cast<const uint4*>(s);                                  \
    g = t + 1536;     row = g >> 5; kk = (g & 31) ^ (row & 7);                 \
    gm = min((tl) * 64 + row, M - 1);                                          \
    s = (kk < 16) ? Xb + (size_t)gm * 128 + kk * 8                             \
                  : Gb + (size_t)gm * 128 + (kk - 16) * 8;                     \
    xr3 = *reinterpret_cast<const uint4*>(s);                                  \
  }
#define WRITEX()                                                               \
  {                                                                            \
    *reinterpret_cast<uint4*>(Xs + (size_t)t * 16) = xr0;                      \
    *reinterpret_cast<uint4*>(Xs + (size_t)(t + 512) * 16) = xr1;              \
    *reinterpret_cast<uint4*>(Xs + (size_t)(t + 1024) * 16) = xr2;             \
    *reinterpret_cast<uint4*>(Xs + (size_t)(t + 1536) * 16) = xr3;             \
  }

  LOADX(tile);
  WRITEX();        // implicit vmcnt wait covers W GLDS (older) + X loads
  __syncthreads(); // once at start: W + X(0) visible

  while (true) {
    int next = tile + gridDim.x;
    bool more = (next < ntiles);
    if (more) LOADX(next);  // prefetch; hidden under GEMM1+GEMM2

    // ---- GEMM1: 64x128, K=256; A from Xs, B from W1s ----
    f32x4 acc[2][2] = {};
#pragma unroll
    for (int ks = 0; ks < 8; ks++) {
      int ga = ks * 4 + (lane >> 4);
      short8 af[2], bf[2];
#pragma unroll
      for (int fm = 0; fm < 2; fm++) {
        int row = wm * 32 + fm * 16 + (lane & 15);
        af[fm] = *reinterpret_cast<const short8*>(
            Xs + row * 512 + ((ga ^ (row & 7)) << 4));
      }
#pragma unroll
      for (int fn = 0; fn < 2; fn++) {
        int colr = wn * 32 + fn * 16 + (lane & 15);
        bf[fn] = *reinterpret_cast<const short8*>(
            (char*)W1s + colr * 512 + ((ga ^ (colr & 7)) << 4));
      }
#pragma unroll
      for (int fm = 0; fm < 2; fm++)
#pragma unroll
        for (int fn = 0; fn < 2; fn++)
          acc[fm][fn] = __builtin_amdgcn_mfma_f32_16x16x32_bf16(
              af[fm], bf[fn], acc[fm][fn], 0, 0, 0);
    }

    __builtin_amdgcn_s_barrier();  // all X reads done (WAR before h1 write)
    FENCE();

    // ---- epi1: h1 = relu(acc+b1) -> Xs[0,16KB) (256B rows, swz gran^(row&7))
#pragma unroll
    for (int fn = 0; fn < 2; fn++) {
      int colg = wn * 32 + fn * 16 + (lane & 15);
      int gg = colg >> 3, cb = (colg & 7) * 2;
#pragma unroll
      for (int fm = 0; fm < 2; fm++) {
#pragma unroll
        for (int r = 0; r < 4; r++) {
          int rowl = wm * 32 + fm * 16 + (lane >> 4) * 4 + r;
          ushort hv = f2bf(fmaxf(acc[fm][fn][r] + bb1[fn], 0.f));
          *reinterpret_cast<ushort*>(
              Xs + rowl * 256 + ((gg ^ (rowl & 7)) << 4) + cb) = hv;
        }
      }
    }
    LGKM0();
    __builtin_amdgcn_s_barrier();  // h1 visible
    FENCE();

    // ---- GEMM2: 64x128, K=128; A=h1 (Xs), B from W2s ----
    f32x4 acc2[2][2] = {};
#pragma unroll
    for (int ks = 0; ks < 4; ks++) {
      int gk = ks * 4 + (lane >> 4);
      short8 af[2], bf[2];
#pragma unroll
      for (int fm = 0; fm < 2; fm++) {
        int row = wm * 32 + fm * 16 + (lane & 15);
        af[fm] = *reinterpret_cast<const short8*>(
            Xs + row * 256 + ((gk ^ (row & 7)) << 4));
      }
#pragma unroll
      for (int fn = 0; fn < 2; fn++) {
        int colr = wn * 32 + fn * 16 + (lane & 15);
        bf[fn] = *reinterpret_cast<const short8*>(
            (char*)W2s + colr * 256 + ((gk ^ (colr & 7)) << 4));
      }
#pragma unroll
      for (int fm = 0; fm < 2; fm++)
#pragma unroll
        for (int fn = 0; fn < 2; fn++)
          acc2[fm][fn] = __builtin_amdgcn_mfma_f32_16x16x32_bf16(
              af[fm], bf[fn], acc2[fm][fn], 0, 0, 0);
    }

    // ---- epi2: wn<2 -> p8 (fp8), wn>=2 -> s2 (f32+b2); wave-uniform split ----
#pragma unroll
    for (int fn = 0; fn < 2; fn++) {
      int colg = wn * 32 + fn * 16 + (lane & 15);
#pragma unroll
      for (int fm = 0; fm < 2; fm++) {
#pragma unroll
        for (int r = 0; r < 4; r++) {
          int rowg = tile * 64 + wm * 32 + fm * 16 + (lane >> 4) * 4 + r;
          if (rowg >= M) continue;
          if (colg < 64) {
            float v = acc2[fm][fn][r];
            int b8 = __builtin_amdgcn_cvt_pk_fp8_f32(v, v, 0, false);
            P8[(size_t)rowg * 64 + colg] = (uchar)(b8 & 0xff);
          } else {
            S2[(size_t)rowg * 64 + (colg - 64)] = acc2[fm][fn][r] + bb2[fn];
          }
        }
      }
    }

    if (!more) break;
    __builtin_amdgcn_s_barrier();  // h1/X reads done (WAR before X overwrite)
    FENCE();
    WRITEX();                      // implicit vmcnt wait on prefetch regs
    LGKM0();
    __builtin_amdgcn_s_barrier();  // X(next) visible
    FENCE();
    tile = next;
  }
#undef LOADX
#undef WRITEX
}

extern "C" void kernel_launch(void* const* d_in, const int* in_sizes, int n_in,
                              void* d_out, int out_size, void* d_ws, size_t ws_size,
                              hipStream_t stream) {
  const float* h = (const float*)d_in[0];
  const int* esrc = (const int*)d_in[1];
  const int* edst = (const int*)d_in[2];
  const float* Ws1 = (const float*)d_in[3];
  const float* Wn1 = (const float*)d_in[4];
  const float* b1 = (const float*)d_in[5];
  const float* Ws2 = (const float*)d_in[6];
  const float* Wn2 = (const float*)d_in[7];
  const float* b2 = (const float*)d_in[8];
  float* out = (float*)d_out;

  const int N = in_sizes[0] / 128;  // 100000
  const int E = in_sizes[1];        // 1600000
  const int P = (N + 255) >> 8;     // 391 buckets (<=512)

  char* base = (char*)d_ws;
  size_t off = 0;
  auto alloc = [&](size_t bytes) {
    size_t o = off;
    off += (bytes + 255) & ~(size_t)255;
    return o;
  };
  int* deg = (int*)(base + alloc((size_t)N * 4));
  int* rs = (int*)(base + alloc((size_t)N * 4));
  int* bcnt = (int*)(base + alloc(513 * 4));
  int* bbase = (int*)(base + alloc(513 * 4));
  int* bcur = (int*)(base + alloc(513 * 4));
  uint* bed = (uint*)(base + alloc((size_t)E * 4));
  int* col = (int*)(base + alloc((size_t)E * 4));
  ushort* hb = (ushort*)(base + alloc((size_t)N * 128 * 2));
  uchar* h8 = (uchar*)(base + alloc((size_t)N * 128));
  ushort* aggb = (ushort*)(base + alloc((size_t)N * 128 * 2));
  ushort* Wt1 = (ushort*)(base + alloc(128 * 256 * 2));
  ushort* Wt2cat = (ushort*)(base + alloc(128 * 128 * 2));
  // overlays:
  uchar* p8 = (uchar*)bed;   // [N][64] fp8: bed dead after k_bcsr; N*64 <= E*4
  float* s2f = (float*)aggb; // [N][64] f32: row ranges owned by the writing tile

  const int NCH = (E + 8191) / 8192;
  const int NT = (N + 63) / 64;  // 1563 M-tiles

  (void)hipMemsetAsync(bcnt, 0, 513 * 4, stream);
  k_bhist<<<NCH, 256, 0, stream>>>(edst, bcnt, E);
  k_bscan<<<1, 512, 0, stream>>>(bcnt, bbase, bcur, P, E);
  k_bscatter<<<NCH, 256, 0, stream>>>(edst, esrc, bcur, bed, E, P);
  k_bcsr<<<P, 256, 0, stream>>>(bed, bbase, deg, rs, col, N);

  k_prep_w<<<((128 * 256 + 128 * 128) + 255) / 256, 256, 0, stream>>>(
      Ws1, Wn1, Ws2, Wn2, Wt1, Wt2cat);
  k_cast<<<((N * 128 / 8) + 255) / 256, 256, 0, stream>>>(h, hb, h8, N * 128 / 8);

  // Layer 1 aggregate, then persistent fused GEMM1+GEMM2 -> p2 (fp8) + s2 (f32)
  k_agg1<<<(N + 31) / 32, 256, 0, stream>>>(h8, col, rs, deg, aggb, N);
  k_persist<<<256, 512, 0, stream>>>(hb, aggb, Wt1, Wt2cat, b1, b2, p8, s2f, N, NT);
  // Layer 2 fused gather + add + relu
  k_agg_out<<<(N + 63) / 64, 256, 0, stream>>>(p8, s2f, col, rs, deg, out, N);
}